// Round 1
// baseline (539.464 us; speedup 1.0000x reference)
//
#include <hip/hip_runtime.h>

// Problem constants
#define NB 8
#define NC 256
#define NHW 1024   // H*W
#define NL 4
#define NG 4
#define NK 2048
#define ND 64      // C/G

#define TN 64      // rows (n) per block
#define TK 64      // codewords per LDS tile
#define LDP 68     // padded LDS stride (floats): 68*4=272 bytes, 16B aligned, bank step 4

// ws[(l*NG+g)*NK + k] = 0.5 * sum_d cb[l][g][k][d]^2
__global__ void cq_cnorm_kernel(const float* __restrict__ cb, float* __restrict__ cn) {
    int idx = blockIdx.x * 256 + threadIdx.x;   // exactly NL*NG*NK threads
    const float4* p = reinterpret_cast<const float4*>(cb + (size_t)idx * ND);
    float s = 0.f;
#pragma unroll
    for (int i = 0; i < ND / 4; ++i) {
        float4 v = p[i];
        s += v.x * v.x + v.y * v.y + v.z * v.z + v.w * v.w;
    }
    cn[idx] = 0.5f * s;
}

__global__ __launch_bounds__(256) void cq_main_kernel(
    const float* __restrict__ x, const float* __restrict__ cb,
    const float* __restrict__ cn, float* __restrict__ out)
{
    __shared__ float r_lds[TN][LDP];
    __shared__ float xh_lds[TN][LDP];
    __shared__ float cb_lds[TK][LDP];
    __shared__ int   ks_lds[TN];

    const int tid   = threadIdx.x;
    const int blk   = blockIdx.x;      // 512 = 32 (b,g) * 16 n-tiles
    const int ntile = blk & 15;
    const int bg    = blk >> 4;
    const int g     = bg & 3;
    const int b     = bg >> 2;
    const int n0    = ntile * TN;

    // x is [B, C, HW] with C = g*ND + d  ->  r[n][d] = x[b][g*ND+d][n0+n]
    const float* xb = x + ((size_t)(b * NC + g * ND)) * NHW + n0;
#pragma unroll
    for (int i = 0; i < (TN * ND) / 256; ++i) {
        int idx = tid + i * 256;
        int d = idx >> 6;
        int n = idx & 63;
        r_lds[n][d]  = xb[(size_t)d * NHW + n];
        xh_lds[n][d] = 0.f;
    }
    // (visibility guaranteed by the barrier at the top of the k0 loop)

    const int tx = tid & 15;   // k dimension (16 lanes)
    const int ty = tid >> 4;   // row dimension (16 groups of 4 rows)

    for (int l = 0; l < NL; ++l) {
        const float* cbl = cb + (size_t)(l * NG + g) * NK * ND;
        const float* cnl = cn + (size_t)(l * NG + g) * NK;

        float minv[4];
        int   mini[4];
#pragma unroll
        for (int i = 0; i < 4; ++i) { minv[i] = 3.4e38f; mini[i] = 0; }

        for (int k0 = 0; k0 < NK; k0 += TK) {
            __syncthreads();   // prior tile fully consumed / r update visible
#pragma unroll
            for (int i = 0; i < (TK * ND) / 256; ++i) {
                int idx = tid + i * 256;
                int kk = idx >> 6;
                int d  = idx & 63;
                cb_lds[kk][d] = cbl[(size_t)(k0 + kk) * ND + d];
            }
            __syncthreads();

            // score = 0.5*||c||^2 - r.c  (same argmin as full ||r-c||^2)
            float acc[4][4];
#pragma unroll
            for (int j = 0; j < 4; ++j) {
                float c = cnl[k0 + tx + 16 * j];
#pragma unroll
                for (int i = 0; i < 4; ++i) acc[i][j] = c;
            }

#pragma unroll
            for (int d0 = 0; d0 < ND; d0 += 4) {
                float4 a[4], bb[4];
#pragma unroll
                for (int i = 0; i < 4; ++i)
                    a[i] = *reinterpret_cast<const float4*>(&r_lds[ty * 4 + i][d0]);
#pragma unroll
                for (int j = 0; j < 4; ++j)
                    bb[j] = *reinterpret_cast<const float4*>(&cb_lds[tx + 16 * j][d0]);
#pragma unroll
                for (int i = 0; i < 4; ++i)
#pragma unroll
                    for (int j = 0; j < 4; ++j) {
                        acc[i][j] = fmaf(-a[i].x, bb[j].x, acc[i][j]);
                        acc[i][j] = fmaf(-a[i].y, bb[j].y, acc[i][j]);
                        acc[i][j] = fmaf(-a[i].z, bb[j].z, acc[i][j]);
                        acc[i][j] = fmaf(-a[i].w, bb[j].w, acc[i][j]);
                    }
            }

#pragma unroll
            for (int i = 0; i < 4; ++i)
#pragma unroll
                for (int j = 0; j < 4; ++j) {
                    int kk = k0 + tx + 16 * j;
                    if (acc[i][j] < minv[i] ||
                        (acc[i][j] == minv[i] && kk < mini[i])) {
                        minv[i] = acc[i][j];
                        mini[i] = kk;
                    }
                }
        }

        // combine across the 16 tx lanes (low 4 bits of lane id); ties -> lower index
#pragma unroll
        for (int m = 1; m < 16; m <<= 1) {
#pragma unroll
            for (int i = 0; i < 4; ++i) {
                float ov = __shfl_xor(minv[i], m, 64);
                int   oi = __shfl_xor(mini[i], m, 64);
                if (ov < minv[i] || (ov == minv[i] && oi < mini[i])) {
                    minv[i] = ov;
                    mini[i] = oi;
                }
            }
        }
        if (tx == 0) {
#pragma unroll
            for (int i = 0; i < 4; ++i) ks_lds[ty * 4 + i] = mini[i];
        }
        __syncthreads();

        // q = cb[k*]; r -= q; xhat += q   (coalesced 256B global reads, L2-hot)
#pragma unroll
        for (int i = 0; i < (TN * ND) / 256; ++i) {
            int idx = tid + i * 256;
            int n = idx >> 6;
            int d = idx & 63;
            float v = cbl[(size_t)ks_lds[n] * ND + d];
            r_lds[n][d]  -= v;
            xh_lds[n][d] += v;
        }
        __syncthreads();
    }

    // out[b][g*ND+d][n0+n] = xhat[n][d]
#pragma unroll
    for (int i = 0; i < (TN * ND) / 256; ++i) {
        int idx = tid + i * 256;
        int d = idx >> 6;
        int n = idx & 63;
        out[((size_t)(b * NC + g * ND + d)) * NHW + n0 + n] = xh_lds[n][d];
    }
}

extern "C" void kernel_launch(void* const* d_in, const int* in_sizes, int n_in,
                              void* d_out, int out_size, void* d_ws, size_t ws_size,
                              hipStream_t stream) {
    const float* x  = (const float*)d_in[0];   // [B, C, H, W]
    const float* cb = (const float*)d_in[1];   // [L, G, K, D]
    float* out = (float*)d_out;
    float* cn  = (float*)d_ws;                 // NL*NG*NK floats = 128 KB

    cq_cnorm_kernel<<<(NL * NG * NK) / 256, 256, 0, stream>>>(cb, cn);
    cq_main_kernel<<<NB * NG * (NHW / TN), 256, 0, stream>>>(x, cb, cn, out);
}

// Round 2
// 186.419 us; speedup vs baseline: 2.8938x; 2.8938x over previous
//
#include <hip/hip_runtime.h>

#define NB 8
#define NC 256
#define NHW 1024   // H*W
#define NL 4
#define NG 4
#define NK 2048
#define ND 64      // C/G

#define RS 68      // r_lds row stride (floats): 272B, 16B-aligned, 2-way-free b128 reads
#define CS 72      // codebook LDS row stride (halfs): 144B, 16B-aligned, 2-way-free

typedef __attribute__((ext_vector_type(8))) _Float16 f16x8;
typedef __attribute__((ext_vector_type(4))) _Float16 f16x4;
typedef __attribute__((ext_vector_type(4))) float    f32x4;

// ws[(l*NG+g)*NK + k] = 0.5 * sum_d cb[l][g][k][d]^2   (exact fp32)
__global__ void cq_cnorm_kernel(const float* __restrict__ cb, float* __restrict__ cn) {
    int idx = blockIdx.x * 256 + threadIdx.x;   // NL*NG*NK threads total
    const float4* p = reinterpret_cast<const float4*>(cb + (size_t)idx * ND);
    float s = 0.f;
#pragma unroll
    for (int i = 0; i < ND / 4; ++i) {
        float4 v = p[i];
        s += v.x * v.x + v.y * v.y + v.z * v.z + v.w * v.w;
    }
    cn[idx] = 0.5f * s;
}

// fp16 hi/lo split: v = h + l + O(2^-24 v). Products h*h etc are exact in fp32.
__device__ __forceinline__ void fsplit(float v, _Float16& h, _Float16& l) {
    _Float16 hh = (_Float16)v;           // v_cvt_f16_f32 (RNE)
    h = hh;
    l = (_Float16)(v - (float)hh);
}

__global__ __launch_bounds__(256, 1) void cq_main_kernel(
    const float* __restrict__ x, const float* __restrict__ cb,
    const float* __restrict__ cn, float* __restrict__ out)
{
    // 111 KB LDS total -> 1 block/CU (grid 256 = 1 per CU)
    __shared__ float    r_lds[128][RS];
    __shared__ _Float16 cbh_lds[2][128][CS];
    __shared__ _Float16 cbl_lds[2][128][CS];
    __shared__ float    mv_lds[2][128];
    __shared__ int      mi_lds[2][128];
    __shared__ int      ks_lds[128];

    const int tid = threadIdx.x;
    const int blk = blockIdx.x;    // 256 = 8b * 4g * 8 n-tiles
    const int nt  = blk & 7;
    const int bg  = blk >> 3;
    const int g   = bg & 3;
    const int b   = bg >> 2;
    const int n0  = nt * 128;

    const float* xb = x + ((size_t)(b * NC + g * ND)) * NHW + n0;

    // load x -> r_lds ; r[n][d] = x[b][g*ND+d][n0+n]  (coalesced float4 over n)
#pragma unroll
    for (int dd = 0; dd < 8; ++dd) {
        int d = (tid >> 5) + dd * 8;
        int n = (tid & 31) * 4;
        float4 xv = *reinterpret_cast<const float4*>(&xb[(size_t)d * NHW + n]);
        r_lds[n + 0][d] = xv.x; r_lds[n + 1][d] = xv.y;
        r_lds[n + 2][d] = xv.z; r_lds[n + 3][d] = xv.w;
    }

    const int lane = tid & 63;
    const int wid  = tid >> 6;
    const int rg   = wid & 1;    // row-group: rows [rg*64, rg*64+64)
    const int kh   = wid >> 1;   // k-half:    k in [kh*1024, kh*1024+1024)
    const int l4   = lane & 15;
    const int l16  = lane >> 4;

    __syncthreads();

    for (int l = 0; l < NL; ++l) {
        const float* cbl_g = cb + (size_t)(l * NG + g) * NK * ND;
        const float* cnl   = cn + (size_t)(l * NG + g) * NK;

        // ---- build negated A fragments (rows rg*64+ns*16+l4, d = c*32+l16*8+j) ----
        f16x8 ah[4][2], al[4][2];
#pragma unroll
        for (int ns = 0; ns < 4; ++ns) {
#pragma unroll
            for (int c = 0; c < 2; ++c) {
                const float* rp = &r_lds[rg * 64 + ns * 16 + l4][c * 32 + l16 * 8];
                float4 v0 = *reinterpret_cast<const float4*>(rp);
                float4 v1 = *reinterpret_cast<const float4*>(rp + 4);
                _Float16 h, lo; f16x8 hv, lv;
                fsplit(-v0.x, h, lo); hv[0] = h; lv[0] = lo;
                fsplit(-v0.y, h, lo); hv[1] = h; lv[1] = lo;
                fsplit(-v0.z, h, lo); hv[2] = h; lv[2] = lo;
                fsplit(-v0.w, h, lo); hv[3] = h; lv[3] = lo;
                fsplit(-v1.x, h, lo); hv[4] = h; lv[4] = lo;
                fsplit(-v1.y, h, lo); hv[5] = h; lv[5] = lo;
                fsplit(-v1.z, h, lo); hv[6] = h; lv[6] = lo;
                fsplit(-v1.w, h, lo); hv[7] = h; lv[7] = lo;
                ah[ns][c] = hv; al[ns][c] = lv;
            }
        }

        float minv[4][4];
        int   mini[4][4];
#pragma unroll
        for (int i = 0; i < 4; ++i)
#pragma unroll
            for (int j = 0; j < 4; ++j) { minv[i][j] = 3.4e38f; mini[i][j] = 0; }

        // ---- prologue: stage 0 (128 k-rows: kh0 -> s*64.., kh1 -> 1024+s*64..) ----
        float4 sreg[8];
#pragma unroll
        for (int p = 0; p < 8; ++p) {
            int kk = p * 16 + (tid >> 4);
            int kg = (kk < 64) ? kk : (1024 - 64 + kk);
            sreg[p] = *reinterpret_cast<const float4*>(&cbl_g[(size_t)kg * ND + (tid & 15) * 4]);
        }
#pragma unroll
        for (int p = 0; p < 8; ++p) {
            int kk = p * 16 + (tid >> 4);
            float4 v = sreg[p];
            _Float16 h, lo; f16x4 hv, lv;
            fsplit(v.x, h, lo); hv[0] = h; lv[0] = lo;
            fsplit(v.y, h, lo); hv[1] = h; lv[1] = lo;
            fsplit(v.z, h, lo); hv[2] = h; lv[2] = lo;
            fsplit(v.w, h, lo); hv[3] = h; lv[3] = lo;
            *reinterpret_cast<f16x4*>(&cbh_lds[0][kk][(tid & 15) * 4]) = hv;
            *reinterpret_cast<f16x4*>(&cbl_lds[0][kk][(tid & 15) * 4]) = lv;
        }

        for (int s = 0; s < 16; ++s) {
            __syncthreads();   // stage s writes visible; dbuf partner free

            if (s < 15) {      // issue next-stage global loads early (hide under MFMA)
#pragma unroll
                for (int p = 0; p < 8; ++p) {
                    int kk = p * 16 + (tid >> 4);
                    int kg = (kk < 64) ? ((s + 1) * 64 + kk) : (1024 + (s + 1) * 64 + (kk - 64));
                    sreg[p] = *reinterpret_cast<const float4*>(&cbl_g[(size_t)kg * ND + (tid & 15) * 4]);
                }
            }

            const int buf = s & 1;
            for (int ks = 0; ks < 4; ++ks) {
                int lrow = kh * 64 + ks * 16 + l4;
                int kabs = kh * 1024 + s * 64 + ks * 16 + l4;
                f16x8 bh0 = *reinterpret_cast<const f16x8*>(&cbh_lds[buf][lrow][l16 * 8]);
                f16x8 bh1 = *reinterpret_cast<const f16x8*>(&cbh_lds[buf][lrow][32 + l16 * 8]);
                f16x8 bl0 = *reinterpret_cast<const f16x8*>(&cbl_lds[buf][lrow][l16 * 8]);
                f16x8 bl1 = *reinterpret_cast<const f16x8*>(&cbl_lds[buf][lrow][32 + l16 * 8]);
                float cnv = cnl[kabs];
                f32x4 acc[4];
#pragma unroll
                for (int ns = 0; ns < 4; ++ns) acc[ns] = (f32x4){cnv, cnv, cnv, cnv};
#pragma unroll
                for (int ns = 0; ns < 4; ++ns) {
                    acc[ns] = __builtin_amdgcn_mfma_f32_16x16x32_f16(ah[ns][0], bh0, acc[ns], 0, 0, 0);
                    acc[ns] = __builtin_amdgcn_mfma_f32_16x16x32_f16(ah[ns][1], bh1, acc[ns], 0, 0, 0);
                    acc[ns] = __builtin_amdgcn_mfma_f32_16x16x32_f16(ah[ns][0], bl0, acc[ns], 0, 0, 0);
                    acc[ns] = __builtin_amdgcn_mfma_f32_16x16x32_f16(ah[ns][1], bl1, acc[ns], 0, 0, 0);
                    acc[ns] = __builtin_amdgcn_mfma_f32_16x16x32_f16(al[ns][0], bh0, acc[ns], 0, 0, 0);
                    acc[ns] = __builtin_amdgcn_mfma_f32_16x16x32_f16(al[ns][1], bh1, acc[ns], 0, 0, 0);
                }
                // running argmin; strict < keeps lowest k (ascending in-lane order)
#pragma unroll
                for (int ns = 0; ns < 4; ++ns)
#pragma unroll
                    for (int j = 0; j < 4; ++j) {
                        float sc = acc[ns][j];
                        bool lt = sc < minv[ns][j];
                        minv[ns][j] = lt ? sc : minv[ns][j];
                        mini[ns][j] = lt ? kabs : mini[ns][j];
                    }
            }

            if (s < 15) {      // convert + write next stage (conflict-free b64 writes)
                const int nbuf = (s + 1) & 1;
#pragma unroll
                for (int p = 0; p < 8; ++p) {
                    int kk = p * 16 + (tid >> 4);
                    float4 v = sreg[p];
                    _Float16 h, lo; f16x4 hv, lv;
                    fsplit(v.x, h, lo); hv[0] = h; lv[0] = lo;
                    fsplit(v.y, h, lo); hv[1] = h; lv[1] = lo;
                    fsplit(v.z, h, lo); hv[2] = h; lv[2] = lo;
                    fsplit(v.w, h, lo); hv[3] = h; lv[3] = lo;
                    *reinterpret_cast<f16x4*>(&cbh_lds[nbuf][kk][(tid & 15) * 4]) = hv;
                    *reinterpret_cast<f16x4*>(&cbl_lds[nbuf][kk][(tid & 15) * 4]) = lv;
                }
            }
        }

        // ---- reduce across the 16 k-lanes (ties -> lower index) ----
#pragma unroll
        for (int m = 1; m < 16; m <<= 1) {
#pragma unroll
            for (int ns = 0; ns < 4; ++ns)
#pragma unroll
                for (int j = 0; j < 4; ++j) {
                    float ov = __shfl_xor(minv[ns][j], m, 64);
                    int   oi = __shfl_xor(mini[ns][j], m, 64);
                    if (ov < minv[ns][j] || (ov == minv[ns][j] && oi < mini[ns][j])) {
                        minv[ns][j] = ov; mini[ns][j] = oi;
                    }
                }
        }
        if (l4 == 0) {
#pragma unroll
            for (int ns = 0; ns < 4; ++ns)
#pragma unroll
                for (int j = 0; j < 4; ++j) {
                    int row = rg * 64 + ns * 16 + l16 * 4 + j;   // C/D: row=(lane>>4)*4+reg
                    mv_lds[kh][row] = minv[ns][j];
                    mi_lds[kh][row] = mini[ns][j];
                }
        }
        __syncthreads();
        if (tid < 128) {   // combine k-halves; tie -> half 0 (lower k)
            float v0 = mv_lds[0][tid], v1 = mv_lds[1][tid];
            ks_lds[tid] = (v1 < v0) ? mi_lds[1][tid] : mi_lds[0][tid];
        }
        __syncthreads();

        // ---- r -= cb[k*]  (exact fp32; codebook rows L2-hot) ----
        {
            int n  = tid >> 1;
            int db = (tid & 1) * 32;
            int kw = ks_lds[n];
            const float* qp = &cbl_g[(size_t)kw * ND + db];
#pragma unroll
            for (int i = 0; i < 8; ++i) {
                float4 q  = *reinterpret_cast<const float4*>(&qp[i * 4]);
                float* rp = &r_lds[n][db + i * 4];
                float4 rv = *reinterpret_cast<float4*>(rp);
                rv.x -= q.x; rv.y -= q.y; rv.z -= q.z; rv.w -= q.w;
                *reinterpret_cast<float4*>(rp) = rv;
            }
        }
        __syncthreads();
    }

    // ---- out = x - r_final  (xhat == sum of q's) ----
    float* ob = out + ((size_t)(b * NC + g * ND)) * NHW + n0;
#pragma unroll
    for (int dd = 0; dd < 8; ++dd) {
        int d = (tid >> 5) + dd * 8;
        int n = (tid & 31) * 4;
        float4 xv = *reinterpret_cast<const float4*>(&xb[(size_t)d * NHW + n]);
        float4 ov;
        ov.x = xv.x - r_lds[n + 0][d];
        ov.y = xv.y - r_lds[n + 1][d];
        ov.z = xv.z - r_lds[n + 2][d];
        ov.w = xv.w - r_lds[n + 3][d];
        *reinterpret_cast<float4*>(&ob[(size_t)d * NHW + n]) = ov;
    }
}

extern "C" void kernel_launch(void* const* d_in, const int* in_sizes, int n_in,
                              void* d_out, int out_size, void* d_ws, size_t ws_size,
                              hipStream_t stream) {
    const float* x  = (const float*)d_in[0];   // [B, C, H, W]
    const float* cb = (const float*)d_in[1];   // [L, G, K, D]
    float* out = (float*)d_out;
    float* cn  = (float*)d_ws;                 // 128 KB

    cq_cnorm_kernel<<<(NL * NG * NK) / 256, 256, 0, stream>>>(cb, cn);
    cq_main_kernel<<<NB * NG * (NHW / 128), 256, 0, stream>>>(x, cb, cn, out);
}

// Round 3
// 116.213 us; speedup vs baseline: 4.6420x; 1.6041x over previous
//
#include <hip/hip_runtime.h>

#define NB 8
#define NC 256
#define NHW 1024   // H*W
#define NL 4
#define NG 4
#define NK 2048
#define ND 64      // C/G

#define RS 68      // r_lds row stride (floats)
#define CS 72      // (fallback kernel) codebook LDS row stride (halfs)

typedef __attribute__((ext_vector_type(8))) _Float16 f16x8;
typedef __attribute__((ext_vector_type(4))) _Float16 f16x4;
typedef __attribute__((ext_vector_type(4))) float    f32x4;

// fp16 hi/lo split: v = h + l + O(2^-24 v). Products h*h etc are exact in fp32.
__device__ __forceinline__ void fsplit(float v, _Float16& h, _Float16& l) {
    _Float16 hh = (_Float16)v;
    h = hh;
    l = (_Float16)(v - (float)hh);
}

// ---------------- fast path: prep kernel ----------------
// For each 16-codeword tile, write 4 fragments (hiC0, hiC1, loC0, loC1),
// each 64 lanes x 8 halfs, in lane-linear order (so main-kernel loads are
// one dwordx4 per lane). Fused: cn[k] = 0.5*||c_k||^2.
__global__ void cq_prep_kernel(const float* __restrict__ cb,
                               _Float16* __restrict__ wfrag,
                               float* __restrict__ cn) {
    int wv   = (blockIdx.x * 256 + threadIdx.x) >> 6;  // tile id 0..2047
    int lane = threadIdx.x & 63;
    int l4 = lane & 15, l16 = lane >> 4;
    int lg = wv >> 7, kt = wv & 127;
    int k  = kt * 16 + l4;
    const float* src = cb + ((size_t)lg * NK + k) * ND;

    float4 a0 = *(const float4*)(src + l16 * 8);
    float4 a1 = *(const float4*)(src + l16 * 8 + 4);
    float4 b0 = *(const float4*)(src + 32 + l16 * 8);
    float4 b1 = *(const float4*)(src + 32 + l16 * 8 + 4);

    f16x8 h0, lo0, h1, lo1;
    _Float16 h, lo;
    fsplit(a0.x,h,lo); h0[0]=h; lo0[0]=lo;  fsplit(a0.y,h,lo); h0[1]=h; lo0[1]=lo;
    fsplit(a0.z,h,lo); h0[2]=h; lo0[2]=lo;  fsplit(a0.w,h,lo); h0[3]=h; lo0[3]=lo;
    fsplit(a1.x,h,lo); h0[4]=h; lo0[4]=lo;  fsplit(a1.y,h,lo); h0[5]=h; lo0[5]=lo;
    fsplit(a1.z,h,lo); h0[6]=h; lo0[6]=lo;  fsplit(a1.w,h,lo); h0[7]=h; lo0[7]=lo;
    fsplit(b0.x,h,lo); h1[0]=h; lo1[0]=lo;  fsplit(b0.y,h,lo); h1[1]=h; lo1[1]=lo;
    fsplit(b0.z,h,lo); h1[2]=h; lo1[2]=lo;  fsplit(b0.w,h,lo); h1[3]=h; lo1[3]=lo;
    fsplit(b1.x,h,lo); h1[4]=h; lo1[4]=lo;  fsplit(b1.y,h,lo); h1[5]=h; lo1[5]=lo;
    fsplit(b1.z,h,lo); h1[6]=h; lo1[6]=lo;  fsplit(b1.w,h,lo); h1[7]=h; lo1[7]=lo;

    _Float16* outp = wfrag + (size_t)wv * 2048;   // tile = 4096 B = 2048 halfs
    *(f16x8*)(outp +    0 + lane * 8) = h0;
    *(f16x8*)(outp +  512 + lane * 8) = h1;
    *(f16x8*)(outp + 1024 + lane * 8) = lo0;
    *(f16x8*)(outp + 1536 + lane * 8) = lo1;

    float s = a0.x*a0.x + a0.y*a0.y + a0.z*a0.z + a0.w*a0.w
            + a1.x*a1.x + a1.y*a1.y + a1.z*a1.z + a1.w*a1.w
            + b0.x*b0.x + b0.y*b0.y + b0.z*b0.z + b0.w*b0.w
            + b1.x*b1.x + b1.y*b1.y + b1.z*b1.z + b1.w*b1.w;
    s += __shfl_xor(s, 16, 64);
    s += __shfl_xor(s, 32, 64);
    if (l16 == 0) cn[(size_t)lg * NK + k] = 0.5f * s;
}

// ---------------- fast path: main kernel ----------------
// 512 blocks x 256 threads (2 blocks/CU, 2 waves/SIMD). Block owns 64 rows;
// each wave owns a K-quarter (512 cw). B-fragments stream from L2 with
// 1-stage register prefetch. No barriers in the k-loop.
__global__ __launch_bounds__(256, 2) void cq_main3_kernel(
    const float* __restrict__ x, const float* __restrict__ cb,
    const _Float16* __restrict__ wfrag, const float* __restrict__ cn,
    float* __restrict__ out)
{
    __shared__ float r_lds[64][RS];
    __shared__ float mv_lds[4][64];
    __shared__ int   mi_lds[4][64];
    __shared__ int   ks_lds[64];

    const int tid = threadIdx.x;
    const int blk = blockIdx.x;       // 512 = 8b * 4g * 16nt
    const int nt  = blk & 15;
    const int g   = (blk >> 4) & 3;
    const int b   = blk >> 6;
    const int n0  = nt * 64;

    const float* xb = x + ((size_t)(b * NC + g * ND)) * NHW + n0;
#pragma unroll
    for (int dd = 0; dd < 4; ++dd) {
        int d = (tid >> 4) + dd * 16;
        int n = (tid & 15) * 4;
        float4 xv = *(const float4*)(&xb[(size_t)d * NHW + n]);
        r_lds[n + 0][d] = xv.x; r_lds[n + 1][d] = xv.y;
        r_lds[n + 2][d] = xv.z; r_lds[n + 3][d] = xv.w;
    }
    __syncthreads();

    const int lane = tid & 63;
    const int w    = tid >> 6;        // k-quarter
    const int l4   = lane & 15;
    const int l16  = lane >> 4;
    const int kbase = w * 512;

    for (int l = 0; l < NL; ++l) {
        const float* cbl_g = cb + (size_t)(l * NG + g) * NK * ND;
        const float* cnl   = cn + (size_t)(l * NG + g) * NK;
        const _Float16* fb = wfrag + ((size_t)(l * NG + g) * 128 + w * 32) * 2048;

        // negated hi/lo A fragments: rows ns*16+l4, d = c*32 + l16*8 + j
        f16x8 ah[4][2], al[4][2];
#pragma unroll
        for (int ns = 0; ns < 4; ++ns) {
#pragma unroll
            for (int c = 0; c < 2; ++c) {
                const float* rp = &r_lds[ns * 16 + l4][c * 32 + l16 * 8];
                float4 v0 = *(const float4*)(rp);
                float4 v1 = *(const float4*)(rp + 4);
                _Float16 h, lo; f16x8 hv, lv;
                fsplit(-v0.x,h,lo); hv[0]=h; lv[0]=lo;
                fsplit(-v0.y,h,lo); hv[1]=h; lv[1]=lo;
                fsplit(-v0.z,h,lo); hv[2]=h; lv[2]=lo;
                fsplit(-v0.w,h,lo); hv[3]=h; lv[3]=lo;
                fsplit(-v1.x,h,lo); hv[4]=h; lv[4]=lo;
                fsplit(-v1.y,h,lo); hv[5]=h; lv[5]=lo;
                fsplit(-v1.z,h,lo); hv[6]=h; lv[6]=lo;
                fsplit(-v1.w,h,lo); hv[7]=h; lv[7]=lo;
                ah[ns][c] = hv; al[ns][c] = lv;
            }
        }

        float minv[4][4];
        int   mini[4][4];
#pragma unroll
        for (int i = 0; i < 4; ++i)
#pragma unroll
            for (int j = 0; j < 4; ++j) { minv[i][j] = 3.4e38f; mini[i][j] = 0; }

        // prefetch stage 0
        f16x8 c0, c1, c2, c3; float cv;
        {
            const _Float16* p = fb + lane * 8;
            c0 = *(const f16x8*)(p);
            c1 = *(const f16x8*)(p + 512);
            c2 = *(const f16x8*)(p + 1024);
            c3 = *(const f16x8*)(p + 1536);
            cv = cnl[kbase + l4];
        }

#pragma unroll 2
        for (int s = 0; s < 32; ++s) {
            f16x8 p0 = c0, p1 = c1, p2 = c2, p3 = c3; float pv = cv;
            if (s < 31) {   // prefetch next stage (hidden under MFMAs)
                const _Float16* p = fb + (size_t)(s + 1) * 2048 + lane * 8;
                c0 = *(const f16x8*)(p);
                c1 = *(const f16x8*)(p + 512);
                c2 = *(const f16x8*)(p + 1024);
                c3 = *(const f16x8*)(p + 1536);
                cv = cnl[kbase + (s + 1) * 16 + l4];
            }
            const int kabs = kbase + s * 16 + l4;
            f32x4 acc[4];
#pragma unroll
            for (int ns = 0; ns < 4; ++ns) acc[ns] = (f32x4){pv, pv, pv, pv};
#pragma unroll
            for (int ns = 0; ns < 4; ++ns) {
                acc[ns] = __builtin_amdgcn_mfma_f32_16x16x32_f16(ah[ns][0], p0, acc[ns], 0, 0, 0);
                acc[ns] = __builtin_amdgcn_mfma_f32_16x16x32_f16(ah[ns][1], p1, acc[ns], 0, 0, 0);
                acc[ns] = __builtin_amdgcn_mfma_f32_16x16x32_f16(ah[ns][0], p2, acc[ns], 0, 0, 0);
                acc[ns] = __builtin_amdgcn_mfma_f32_16x16x32_f16(ah[ns][1], p3, acc[ns], 0, 0, 0);
                acc[ns] = __builtin_amdgcn_mfma_f32_16x16x32_f16(al[ns][0], p0, acc[ns], 0, 0, 0);
                acc[ns] = __builtin_amdgcn_mfma_f32_16x16x32_f16(al[ns][1], p1, acc[ns], 0, 0, 0);
            }
#pragma unroll
            for (int ns = 0; ns < 4; ++ns)
#pragma unroll
                for (int j = 0; j < 4; ++j) {
                    float sc = acc[ns][j];
                    bool lt = sc < minv[ns][j];
                    minv[ns][j] = lt ? sc : minv[ns][j];
                    mini[ns][j] = lt ? kabs : mini[ns][j];
                }
        }

        // reduce over the 16 k-lanes (ties -> lower k)
#pragma unroll
        for (int m = 1; m < 16; m <<= 1) {
#pragma unroll
            for (int ns = 0; ns < 4; ++ns)
#pragma unroll
                for (int j = 0; j < 4; ++j) {
                    float ov = __shfl_xor(minv[ns][j], m, 64);
                    int   oi = __shfl_xor(mini[ns][j], m, 64);
                    if (ov < minv[ns][j] || (ov == minv[ns][j] && oi < mini[ns][j])) {
                        minv[ns][j] = ov; mini[ns][j] = oi;
                    }
                }
        }
        if (l4 == 0) {
#pragma unroll
            for (int ns = 0; ns < 4; ++ns)
#pragma unroll
                for (int j = 0; j < 4; ++j) {
                    int row = ns * 16 + l16 * 4 + j;   // C/D: row=(lane>>4)*4+reg
                    mv_lds[w][row] = minv[ns][j];
                    mi_lds[w][row] = mini[ns][j];
                }
        }
        __syncthreads();
        if (tid < 64) {   // combine 4 quarters ascending (tie -> lower k)
            float bv = mv_lds[0][tid]; int bi = mi_lds[0][tid];
#pragma unroll
            for (int q = 1; q < 4; ++q) {
                float v = mv_lds[q][tid];
                if (v < bv) { bv = v; bi = mi_lds[q][tid]; }
            }
            ks_lds[tid] = bi;
        }
        __syncthreads();

        // r -= cb[k*]  (exact fp32, rows L2-hot)
        {
            int row = tid >> 2, dc = (tid & 3) * 16;
            int kw = ks_lds[row];
            const float* qp = cbl_g + (size_t)kw * ND + dc;
#pragma unroll
            for (int i = 0; i < 4; ++i) {
                float4 q  = *(const float4*)(qp + i * 4);
                float* rp = &r_lds[row][dc + i * 4];
                float4 rv = *(float4*)rp;
                rv.x -= q.x; rv.y -= q.y; rv.z -= q.z; rv.w -= q.w;
                *(float4*)rp = rv;
            }
        }
        __syncthreads();
    }

    // out = x - r_final
    float* ob = out + ((size_t)(b * NC + g * ND)) * NHW + n0;
#pragma unroll
    for (int dd = 0; dd < 4; ++dd) {
        int d = (tid >> 4) + dd * 16;
        int n = (tid & 15) * 4;
        float4 xv = *(const float4*)(&xb[(size_t)d * NHW + n]);
        float4 ov;
        ov.x = xv.x - r_lds[n + 0][d];
        ov.y = xv.y - r_lds[n + 1][d];
        ov.z = xv.z - r_lds[n + 2][d];
        ov.w = xv.w - r_lds[n + 3][d];
        *(float4*)(&ob[(size_t)d * NHW + n]) = ov;
    }
}

// ---------------- fallback path (round-2 kernel, needs only 128 KB ws) ----------------
__global__ void cq_cnorm_kernel(const float* __restrict__ cb, float* __restrict__ cn) {
    int idx = blockIdx.x * 256 + threadIdx.x;
    const float4* p = reinterpret_cast<const float4*>(cb + (size_t)idx * ND);
    float s = 0.f;
#pragma unroll
    for (int i = 0; i < ND / 4; ++i) {
        float4 v = p[i];
        s += v.x * v.x + v.y * v.y + v.z * v.z + v.w * v.w;
    }
    cn[idx] = 0.5f * s;
}

__global__ __launch_bounds__(256, 1) void cq_main_kernel(
    const float* __restrict__ x, const float* __restrict__ cb,
    const float* __restrict__ cn, float* __restrict__ out)
{
    __shared__ float    r_lds[128][RS];
    __shared__ _Float16 cbh_lds[2][128][CS];
    __shared__ _Float16 cbl_lds[2][128][CS];
    __shared__ float    mv_lds[2][128];
    __shared__ int      mi_lds[2][128];
    __shared__ int      ks_lds[128];

    const int tid = threadIdx.x;
    const int blk = blockIdx.x;
    const int nt  = blk & 7;
    const int bg  = blk >> 3;
    const int g   = bg & 3;
    const int b   = bg >> 2;
    const int n0  = nt * 128;

    const float* xb = x + ((size_t)(b * NC + g * ND)) * NHW + n0;
#pragma unroll
    for (int dd = 0; dd < 8; ++dd) {
        int d = (tid >> 5) + dd * 8;
        int n = (tid & 31) * 4;
        float4 xv = *reinterpret_cast<const float4*>(&xb[(size_t)d * NHW + n]);
        r_lds[n + 0][d] = xv.x; r_lds[n + 1][d] = xv.y;
        r_lds[n + 2][d] = xv.z; r_lds[n + 3][d] = xv.w;
    }

    const int lane = tid & 63;
    const int wid  = tid >> 6;
    const int rg   = wid & 1;
    const int kh   = wid >> 1;
    const int l4   = lane & 15;
    const int l16  = lane >> 4;

    __syncthreads();

    for (int l = 0; l < NL; ++l) {
        const float* cbl_g = cb + (size_t)(l * NG + g) * NK * ND;
        const float* cnl   = cn + (size_t)(l * NG + g) * NK;

        f16x8 ah[4][2], al[4][2];
#pragma unroll
        for (int ns = 0; ns < 4; ++ns) {
#pragma unroll
            for (int c = 0; c < 2; ++c) {
                const float* rp = &r_lds[rg * 64 + ns * 16 + l4][c * 32 + l16 * 8];
                float4 v0 = *reinterpret_cast<const float4*>(rp);
                float4 v1 = *reinterpret_cast<const float4*>(rp + 4);
                _Float16 h, lo; f16x8 hv, lv;
                fsplit(-v0.x, h, lo); hv[0] = h; lv[0] = lo;
                fsplit(-v0.y, h, lo); hv[1] = h; lv[1] = lo;
                fsplit(-v0.z, h, lo); hv[2] = h; lv[2] = lo;
                fsplit(-v0.w, h, lo); hv[3] = h; lv[3] = lo;
                fsplit(-v1.x, h, lo); hv[4] = h; lv[4] = lo;
                fsplit(-v1.y, h, lo); hv[5] = h; lv[5] = lo;
                fsplit(-v1.z, h, lo); hv[6] = h; lv[6] = lo;
                fsplit(-v1.w, h, lo); hv[7] = h; lv[7] = lo;
                ah[ns][c] = hv; al[ns][c] = lv;
            }
        }

        float minv[4][4];
        int   mini[4][4];
#pragma unroll
        for (int i = 0; i < 4; ++i)
#pragma unroll
            for (int j = 0; j < 4; ++j) { minv[i][j] = 3.4e38f; mini[i][j] = 0; }

        float4 sreg[8];
#pragma unroll
        for (int p = 0; p < 8; ++p) {
            int kk = p * 16 + (tid >> 4);
            int kg = (kk < 64) ? kk : (1024 - 64 + kk);
            sreg[p] = *reinterpret_cast<const float4*>(&cbl_g[(size_t)kg * ND + (tid & 15) * 4]);
        }
#pragma unroll
        for (int p = 0; p < 8; ++p) {
            int kk = p * 16 + (tid >> 4);
            float4 v = sreg[p];
            _Float16 h, lo; f16x4 hv, lv;
            fsplit(v.x, h, lo); hv[0] = h; lv[0] = lo;
            fsplit(v.y, h, lo); hv[1] = h; lv[1] = lo;
            fsplit(v.z, h, lo); hv[2] = h; lv[2] = lo;
            fsplit(v.w, h, lo); hv[3] = h; lv[3] = lo;
            *reinterpret_cast<f16x4*>(&cbh_lds[0][kk][(tid & 15) * 4]) = hv;
            *reinterpret_cast<f16x4*>(&cbl_lds[0][kk][(tid & 15) * 4]) = lv;
        }

        for (int s = 0; s < 16; ++s) {
            __syncthreads();

            if (s < 15) {
#pragma unroll
                for (int p = 0; p < 8; ++p) {
                    int kk = p * 16 + (tid >> 4);
                    int kg = (kk < 64) ? ((s + 1) * 64 + kk) : (1024 + (s + 1) * 64 + (kk - 64));
                    sreg[p] = *reinterpret_cast<const float4*>(&cbl_g[(size_t)kg * ND + (tid & 15) * 4]);
                }
            }

            const int buf = s & 1;
            for (int ks = 0; ks < 4; ++ks) {
                int lrow = kh * 64 + ks * 16 + l4;
                int kabs = kh * 1024 + s * 64 + ks * 16 + l4;
                f16x8 bh0 = *reinterpret_cast<const f16x8*>(&cbh_lds[buf][lrow][l16 * 8]);
                f16x8 bh1 = *reinterpret_cast<const f16x8*>(&cbh_lds[buf][lrow][32 + l16 * 8]);
                f16x8 bl0 = *reinterpret_cast<const f16x8*>(&cbl_lds[buf][lrow][l16 * 8]);
                f16x8 bl1 = *reinterpret_cast<const f16x8*>(&cbl_lds[buf][lrow][32 + l16 * 8]);
                float cnv = cnl[kabs];
                f32x4 acc[4];
#pragma unroll
                for (int ns = 0; ns < 4; ++ns) acc[ns] = (f32x4){cnv, cnv, cnv, cnv};
#pragma unroll
                for (int ns = 0; ns < 4; ++ns) {
                    acc[ns] = __builtin_amdgcn_mfma_f32_16x16x32_f16(ah[ns][0], bh0, acc[ns], 0, 0, 0);
                    acc[ns] = __builtin_amdgcn_mfma_f32_16x16x32_f16(ah[ns][1], bh1, acc[ns], 0, 0, 0);
                    acc[ns] = __builtin_amdgcn_mfma_f32_16x16x32_f16(ah[ns][0], bl0, acc[ns], 0, 0, 0);
                    acc[ns] = __builtin_amdgcn_mfma_f32_16x16x32_f16(ah[ns][1], bl1, acc[ns], 0, 0, 0);
                    acc[ns] = __builtin_amdgcn_mfma_f32_16x16x32_f16(al[ns][0], bh0, acc[ns], 0, 0, 0);
                    acc[ns] = __builtin_amdgcn_mfma_f32_16x16x32_f16(al[ns][1], bh1, acc[ns], 0, 0, 0);
                }
#pragma unroll
                for (int ns = 0; ns < 4; ++ns)
#pragma unroll
                    for (int j = 0; j < 4; ++j) {
                        float sc = acc[ns][j];
                        bool lt = sc < minv[ns][j];
                        minv[ns][j] = lt ? sc : minv[ns][j];
                        mini[ns][j] = lt ? kabs : mini[ns][j];
                    }
            }

            if (s < 15) {
                const int nbuf = (s + 1) & 1;
#pragma unroll
                for (int p = 0; p < 8; ++p) {
                    int kk = p * 16 + (tid >> 4);
                    float4 v = sreg[p];
                    _Float16 h, lo; f16x4 hv, lv;
                    fsplit(v.x, h, lo); hv[0] = h; lv[0] = lo;
                    fsplit(v.y, h, lo); hv[1] = h; lv[1] = lo;
                    fsplit(v.z, h, lo); hv[2] = h; lv[2] = lo;
                    fsplit(v.w, h, lo); hv[3] = h; lv[3] = lo;
                    *reinterpret_cast<f16x4*>(&cbh_lds[nbuf][kk][(tid & 15) * 4]) = hv;
                    *reinterpret_cast<f16x4*>(&cbl_lds[nbuf][kk][(tid & 15) * 4]) = lv;
                }
            }
        }

#pragma unroll
        for (int m = 1; m < 16; m <<= 1) {
#pragma unroll
            for (int ns = 0; ns < 4; ++ns)
#pragma unroll
                for (int j = 0; j < 4; ++j) {
                    float ov = __shfl_xor(minv[ns][j], m, 64);
                    int   oi = __shfl_xor(mini[ns][j], m, 64);
                    if (ov < minv[ns][j] || (ov == minv[ns][j] && oi < mini[ns][j])) {
                        minv[ns][j] = ov; mini[ns][j] = oi;
                    }
                }
        }
        if (l4 == 0) {
#pragma unroll
            for (int ns = 0; ns < 4; ++ns)
#pragma unroll
                for (int j = 0; j < 4; ++j) {
                    int row = rg * 64 + ns * 16 + l16 * 4 + j;
                    mv_lds[kh][row] = minv[ns][j];
                    mi_lds[kh][row] = mini[ns][j];
                }
        }
        __syncthreads();
        if (tid < 128) {
            float v0 = mv_lds[0][tid], v1 = mv_lds[1][tid];
            ks_lds[tid] = (v1 < v0) ? mi_lds[1][tid] : mi_lds[0][tid];
        }
        __syncthreads();

        {
            int n  = tid >> 1;
            int db = (tid & 1) * 32;
            int kw = ks_lds[n];
            const float* qp = &cbl_g[(size_t)kw * ND + db];
#pragma unroll
            for (int i = 0; i < 8; ++i) {
                float4 q  = *reinterpret_cast<const float4*>(&qp[i * 4]);
                float* rp = &r_lds[n][db + i * 4];
                float4 rv = *reinterpret_cast<float4*>(rp);
                rv.x -= q.x; rv.y -= q.y; rv.z -= q.z; rv.w -= q.w;
                *reinterpret_cast<float4*>(rp) = rv;
            }
        }
        __syncthreads();
    }

    float* ob = out + ((size_t)(b * NC + g * ND)) * NHW + n0;
#pragma unroll
    for (int dd = 0; dd < 8; ++dd) {
        int d = (tid >> 5) + dd * 8;
        int n = (tid & 31) * 4;
        float4 xv = *reinterpret_cast<const float4*>(&xb[(size_t)d * NHW + n]);
        float4 ov;
        ov.x = xv.x - r_lds[n + 0][d];
        ov.y = xv.y - r_lds[n + 1][d];
        ov.z = xv.z - r_lds[n + 2][d];
        ov.w = xv.w - r_lds[n + 3][d];
        *reinterpret_cast<float4*>(&ob[(size_t)d * NHW + n]) = ov;
    }
}

extern "C" void kernel_launch(void* const* d_in, const int* in_sizes, int n_in,
                              void* d_out, int out_size, void* d_ws, size_t ws_size,
                              hipStream_t stream) {
    const float* x  = (const float*)d_in[0];   // [B, C, H, W]
    const float* cb = (const float*)d_in[1];   // [L, G, K, D]
    float* out = (float*)d_out;

    const size_t FRAG_BYTES = (size_t)NL * NG * NK * ND * 2 * 2;  // 8 MiB
    const size_t NEED = FRAG_BYTES + (size_t)NL * NG * NK * 4;    // + cn

    if (ws_size >= NEED) {
        _Float16* wfrag = (_Float16*)d_ws;
        float* cn = (float*)((char*)d_ws + FRAG_BYTES);
        cq_prep_kernel<<<512, 256, 0, stream>>>(cb, wfrag, cn);
        cq_main3_kernel<<<NB * NG * (NHW / 64), 256, 0, stream>>>(x, cb, wfrag, cn, out);
    } else {
        float* cn = (float*)d_ws;
        cq_cnorm_kernel<<<(NL * NG * NK) / 256, 256, 0, stream>>>(cb, cn);
        cq_main_kernel<<<NB * NG * (NHW / 128), 256, 0, stream>>>(x, cb, cn, out);
    }
}